// Round 11
// baseline (424.210 us; speedup 1.0000x reference)
//
#include <hip/hip_runtime.h>
#include <hip/hip_cooperative_groups.h>

namespace cg = cooperative_groups;

// ---------------------------------------------------------------------------
// GCN encoder: out = GCNConv2( relu(GCNConv1(x)) )
// R10: single cooperative prep kernel (is64 detect + hist + colscan +
// basescan + scatter + csrbuild + convW) with grid.sync between phases;
// falls back to the R9 multi-kernel chain if coop launch is unavailable.
// GEMM = R7 async-LDS fp16 MFMA. Gathers = R9 clamped 8-edge rounds.
// ---------------------------------------------------------------------------

typedef __attribute__((ext_vector_type(4))) float floatx4;
typedef _Float16 __attribute__((ext_vector_type(8))) half8v;

#define BUCK_SH 6
#define BUCK    64           // dsts per bucket
#define NBLK    256          // blocks for prep/hist/scatter

#define AS1(p) ((const __attribute__((address_space(1))) void*)(p))
#define AS3(p) ((__attribute__((address_space(3))) void*)(p))

__device__ __forceinline__ int edge_id(const int* __restrict__ ei, int is64, long long pos) {
    return is64 ? ei[2 * pos] : ei[(int)pos];
}

// ---------------------------------------------------------------------------
// Weight pre-transform helper: W[K][Nc] fp32 -> Wt [Nc][K] fp16
// ---------------------------------------------------------------------------
__device__ __forceinline__ void convW_one(const float* W, _Float16* Wt, int K, int Nc, int idx) {
    if (idx >= K * Nc) return;
    int k = idx / Nc, n = idx % Nc;
    Wt[(long long)n * K + k] = (_Float16)W[idx];
}

struct PrepParams {
    const int* ei;
    int E, NB, chunk, N;
    int* hist2;        // [NBLK][NB]
    int* start2t;      // [NB][NBLK]
    int* colsum;       // [NB]
    int* bbase;        // [NB+1]
    unsigned* ebuf;    // [E]
    int* offs;         // [N+1]
    float* dinv;       // [N]
    int* csr;          // [E]
    const float* W1; _Float16* W1t;
    const float* W2; _Float16* W2t;
};

// ---------------------------------------------------------------------------
// Cooperative prep: all CSR-build phases in one kernel, 256 blocks x 256 thr.
// ---------------------------------------------------------------------------
__global__ void __launch_bounds__(256) prep_kernel(PrepParams p) {
    cg::grid_group grid = cg::this_grid();
    __shared__ int sh[1024];
    __shared__ int cnt[BUCK], exc[BUCK], cur[BUCK];
    __shared__ int shflag;
    const int t = threadIdx.x;
    const int b = blockIdx.x;

    // per-block is64 detection: int64 node ids (<2^31) => odd dwords all 0
    if (t == 0) shflag = 0;
    __syncthreads();
    if (p.ei[2 * t + 1] != 0) atomicOr(&shflag, 1);
    __syncthreads();
    const int is64 = (shflag == 0) ? 1 : 0;

    const int lo = b * p.chunk;
    const int hi = min(p.E, lo + p.chunk);

    // ---- phase A: per-block bucket histogram of own chunk + convW ---------
    for (int i = t; i < p.NB; i += 256) sh[i] = 0;
    __syncthreads();
    for (int e = lo + t; e < hi; e += 256) {
        int d = edge_id(p.ei, is64, (long long)p.E + e);
        atomicAdd(&sh[d >> BUCK_SH], 1);
    }
    __syncthreads();
    for (int i = t; i < p.NB; i += 256) p.hist2[(long long)b * p.NB + i] = sh[i];
    {
        int gtid = b * 256 + t;                 // 65536 threads cover both Ws
        convW_one(p.W1, p.W1t, 256, 128, gtid);
        int g2 = gtid - 256 * 128;
        if (g2 >= 0) convW_one(p.W2, p.W2t, 128, 64, g2);
    }
    grid.sync();

    // ---- phase B: per-bucket column scan (threads 0..NB-1 across grid) ----
    {
        int gtid = b * 256 + t;
        if (gtid < p.NB) {
            int run = 0;
            for (int b2 = 0; b2 < NBLK; ++b2) {
                int v = p.hist2[(long long)b2 * p.NB + gtid];
                p.start2t[(long long)gtid * NBLK + b2] = run;
                run += v;
            }
            p.colsum[gtid] = run;
        }
    }
    grid.sync();

    // ---- phase C: exclusive scan of colsum -> bbase (block 0) -------------
    if (b == 0) {
        const int C = (p.NB + 255) / 256;       // buckets per thread (<=8)
        int vals[8];
        int mysum = 0;
        for (int i = 0; i < C; ++i) {
            int idx = t * C + i;
            int v = (idx < p.NB) ? p.colsum[idx] : 0;
            vals[i] = v; mysum += v;
        }
        sh[t] = mysum;
        __syncthreads();
        for (int s = 1; s < 256; s <<= 1) {
            int u = (t >= s) ? sh[t - s] : 0;
            __syncthreads();
            sh[t] += u;
            __syncthreads();
        }
        int run = sh[t] - mysum;
        for (int i = 0; i < C; ++i) {
            int idx = t * C + i;
            if (idx < p.NB) { p.bbase[idx] = run; run += vals[i]; }
        }
        if (t == 0) p.bbase[p.NB] = p.E;
    }
    grid.sync();

    // ---- phase D: scatter own chunk with LDS cursors (ei chunk L2-hot) ----
    for (int i = t; i < p.NB; i += 256)
        sh[i] = p.bbase[i] + p.start2t[(long long)i * NBLK + b];
    __syncthreads();
    for (int e = lo + t; e < hi; e += 256) {
        int s = edge_id(p.ei, is64, e);
        int d = edge_id(p.ei, is64, (long long)p.E + e);
        int pos = atomicAdd(&sh[d >> BUCK_SH], 1);
        p.ebuf[pos] = (unsigned)s | ((unsigned)(d & (BUCK - 1)) << 26);
    }
    grid.sync();

    // ---- phase E: per-bucket exact CSR build (block handles b, b+256, ...) -
    for (int bk = b; bk < p.NB; bk += NBLK) {
        if (t < BUCK) { cnt[t] = 0; cur[t] = 0; }
        __syncthreads();
        const int l0 = p.bbase[bk], h0 = p.bbase[bk + 1];
        for (int i = l0 + t; i < h0; i += 256)
            atomicAdd(&cnt[p.ebuf[i] >> 26], 1);
        __syncthreads();
        if (t == 0) {
            int run = 0;
            for (int l = 0; l < BUCK; ++l) { exc[l] = run; run += cnt[l]; }
        }
        __syncthreads();
        if (t < BUCK) {
            int n = bk * BUCK + t;
            if (n < p.N) {
                p.offs[n] = l0 + exc[t];
                p.dinv[n] = rsqrtf(1.0f + (float)cnt[t]);
            }
        }
        if (bk == p.NB - 1 && t == 0) p.offs[p.N] = p.E;
        for (int i = l0 + t; i < h0; i += 256) {
            unsigned e = p.ebuf[i];
            int l = e >> 26;
            int pq = l0 + exc[l] + atomicAdd(&cur[l], 1);
            p.csr[pq] = (int)(e & 0x03FFFFFFu);
        }
        __syncthreads();
    }
}

// ======================= fallback (non-cooperative) chain ===================
__global__ void detect64_kernel(const int* __restrict__ ei, int* __restrict__ flag) {
    __shared__ int nz;
    if (threadIdx.x == 0) nz = 0;
    __syncthreads();
    if (ei[2 * threadIdx.x + 1] != 0) atomicOr(&nz, 1);
    __syncthreads();
    if (threadIdx.x == 0) *flag = (nz == 0) ? 1 : 0;
}

__global__ void hist2_kernel(const int* __restrict__ ei, const int* __restrict__ flag,
                             int* __restrict__ hist2, int E, int NB, int chunk) {
    __shared__ int h[1024];
    const int t = threadIdx.x;
    for (int i = t; i < NB; i += blockDim.x) h[i] = 0;
    __syncthreads();
    const int is64 = *flag;
    const int lo = blockIdx.x * chunk;
    const int hi = min(E, lo + chunk);
    for (int e = lo + t; e < hi; e += blockDim.x) {
        int d = edge_id(ei, is64, (long long)E + e);
        atomicAdd(&h[d >> BUCK_SH], 1);
    }
    __syncthreads();
    for (int i = t; i < NB; i += blockDim.x) hist2[(long long)blockIdx.x * NB + i] = h[i];
}

__global__ void colscan_kernel(const int* __restrict__ hist2, int* __restrict__ start2t,
                               int* __restrict__ colsum, int NB) {
    int t = blockIdx.x * blockDim.x + threadIdx.x;
    if (t >= NB) return;
    int run = 0;
    for (int b = 0; b < NBLK; ++b) {
        int v = hist2[(long long)b * NB + t];
        start2t[(long long)t * NBLK + b] = run;
        run += v;
    }
    colsum[t] = run;
}

__global__ void basescan_kernel(const int* __restrict__ colsum, int* __restrict__ bbase,
                                int NB, int E) {
    __shared__ int sm[1024];
    const int t = threadIdx.x;
    int v = (t < NB) ? colsum[t] : 0;
    sm[t] = v;
    __syncthreads();
    for (int s = 1; s < 1024; s <<= 1) {
        int u = (t >= s) ? sm[t - s] : 0;
        __syncthreads();
        sm[t] += u;
        __syncthreads();
    }
    if (t < NB) bbase[t] = sm[t] - v;
    if (t == 0) bbase[NB] = E;
}

__global__ void scatter2_kernel(const int* __restrict__ ei, const int* __restrict__ flag,
                                const int* __restrict__ bbase, const int* __restrict__ start2t,
                                unsigned* __restrict__ ebuf, int E, int NB, int chunk) {
    __shared__ int hcur[1024];
    const int t = threadIdx.x;
    for (int i = t; i < NB; i += blockDim.x)
        hcur[i] = bbase[i] + start2t[(long long)i * NBLK + blockIdx.x];
    __syncthreads();
    const int is64 = *flag;
    const int lo = blockIdx.x * chunk;
    const int hi = min(E, lo + chunk);
    for (int e = lo + t; e < hi; e += blockDim.x) {
        int s = edge_id(ei, is64, e);
        int d = edge_id(ei, is64, (long long)E + e);
        int pos = atomicAdd(&hcur[d >> BUCK_SH], 1);
        ebuf[pos] = (unsigned)s | ((unsigned)(d & (BUCK - 1)) << 26);
    }
}

__global__ void csrbuild_kernel(const unsigned* __restrict__ ebuf, const int* __restrict__ bbase,
                                int* __restrict__ offs, float* __restrict__ dinv,
                                int* __restrict__ csr, int N, int NB, int E) {
    __shared__ int cnt[BUCK], exc[BUCK], cur[BUCK];
    const int b = blockIdx.x;
    const int t = threadIdx.x;
    if (t < BUCK) { cnt[t] = 0; cur[t] = 0; }
    __syncthreads();
    const int lo = bbase[b], hi = bbase[b + 1];
    for (int i = lo + t; i < hi; i += blockDim.x)
        atomicAdd(&cnt[ebuf[i] >> 26], 1);
    __syncthreads();
    if (t == 0) {
        int run = 0;
        for (int l = 0; l < BUCK; ++l) { exc[l] = run; run += cnt[l]; }
    }
    __syncthreads();
    if (t < BUCK) {
        int n = b * BUCK + t;
        if (n < N) {
            offs[n] = lo + exc[t];
            dinv[n] = rsqrtf(1.0f + (float)cnt[t]);
        }
    }
    if (b == NB - 1 && t == 0) offs[N] = E;
    for (int i = lo + t; i < hi; i += blockDim.x) {
        unsigned e = ebuf[i];
        int l = e >> 26;
        int p = lo + exc[l] + atomicAdd(&cur[l], 1);
        csr[p] = (int)(e & 0x03FFFFFFu);
    }
}

__global__ void convW_kernel(const float* __restrict__ W1, _Float16* __restrict__ T1,
                             int K1, int N1, int nb1,
                             const float* __restrict__ W2, _Float16* __restrict__ T2,
                             int K2, int N2) {
    if ((int)blockIdx.x < nb1) {
        convW_one(W1, T1, K1, N1, blockIdx.x * blockDim.x + threadIdx.x);
    } else {
        convW_one(W2, T2, K2, N2, (blockIdx.x - nb1) * blockDim.x + threadIdx.x);
    }
}
// ======================= end fallback chain =================================

// ---------------------------------------------------------------------------
// fp16 MFMA GEMM: C[M,NCOL](fp16) = A[M,K](fp32) @ B[K,NCOL]
// B pre-transposed fp16 [NCOL][K] (L2-resident). BM=128, BK=64, 4 waves,
// RT=2 row-tiles/wave. A staged fp32 via async global_load_lds (width 16),
// double-buffered, XOR-swizzled 16B units for conflict-free ds_read_b128.
// ---------------------------------------------------------------------------
template <int NCOL, int K>
__launch_bounds__(256)
__global__ void gemm_f16_kernel(const float* __restrict__ A,
                                const _Float16* __restrict__ Bt,
                                _Float16* __restrict__ C, int M) {
    constexpr int NCB = NCOL / 16;
    constexpr int BM = 128, BK = 64;
    constexpr int NC = K / BK;
    constexpr int UNITS = BM * BK / 4;
    __shared__ float As[2][BM * BK];

    const int tid  = threadIdx.x;
    const int wave = tid >> 6;
    const int lane = tid & 63;
    const int n15  = lane & 15;
    const int q    = lane >> 4;
    const int row0 = blockIdx.x * BM;

    floatx4 acc[2][NCB];
#pragma unroll
    for (int rt = 0; rt < 2; ++rt)
#pragma unroll
        for (int c = 0; c < NCB; ++c) acc[rt][c] = (floatx4){0.f, 0.f, 0.f, 0.f};

    auto stage = [&](int buf, int kc) {
#pragma unroll
        for (int j = 0; j < UNITS / 256; ++j) {
            int g = j * 256 + tid;
            int r = g >> 4;
            int u = (g & 15) ^ (r & 15);
            int gr = row0 + r;
            if (gr >= M) gr = M - 1;
            const float* gp = &A[(long long)gr * K + kc + u * 4];
            float* lp = &As[buf][g * 4];
            __builtin_amdgcn_global_load_lds(AS1(gp), AS3(lp), 16, 0, 0);
        }
    };

    stage(0, 0);
    __syncthreads();

#pragma unroll
    for (int c = 0; c < NC; ++c) {
        if (c + 1 < NC) stage((c + 1) & 1, (c + 1) * BK);
        const int buf = c & 1;
#pragma unroll
        for (int ks = 0; ks < 2; ++ks) {
            half8v af[2];
#pragma unroll
            for (int rt = 0; rt < 2; ++rt) {
                const int R = wave * 32 + rt * 16 + n15;
                const int u0 = ks * 8 + q * 2;
                const int p0 = (u0)     ^ (R & 15);
                const int p1 = (u0 + 1) ^ (R & 15);
                float4 f0 = *(const float4*)&As[buf][R * BK + p0 * 4];
                float4 f1 = *(const float4*)&As[buf][R * BK + p1 * 4];
                af[rt][0] = (_Float16)f0.x; af[rt][1] = (_Float16)f0.y;
                af[rt][2] = (_Float16)f0.z; af[rt][3] = (_Float16)f0.w;
                af[rt][4] = (_Float16)f1.x; af[rt][5] = (_Float16)f1.y;
                af[rt][6] = (_Float16)f1.z; af[rt][7] = (_Float16)f1.w;
            }
#pragma unroll
            for (int cb = 0; cb < NCB; ++cb) {
                const _Float16* bp = &Bt[(long long)(cb * 16 + n15) * K + c * BK + ks * 32 + q * 8];
                half8v bf = *(const half8v*)bp;
                acc[0][cb] = __builtin_amdgcn_mfma_f32_16x16x32_f16(af[0], bf, acc[0][cb], 0, 0, 0);
                acc[1][cb] = __builtin_amdgcn_mfma_f32_16x16x32_f16(af[1], bf, acc[1][cb], 0, 0, 0);
            }
        }
        if (c + 1 < NC) __syncthreads();
    }

#pragma unroll
    for (int rt = 0; rt < 2; ++rt) {
#pragma unroll
        for (int cb = 0; cb < NCB; ++cb) {
            int col = cb * 16 + n15;
#pragma unroll
            for (int r = 0; r < 4; ++r) {
                int gr = row0 + wave * 32 + rt * 16 + q * 4 + r;
                if (gr < M) C[(long long)gr * NCOL + col] = (_Float16)acc[rt][cb][r];
            }
        }
    }
}

// ---------------------------------------------------------------------------
// Gather aggregation, fp16 h, 8 channels/lane, clamped 8-edge rounds.
// out[n][:] = (h[n]*dinv[n]^2 + sum_e h[src]*dinv[src]*dinv[n]) + bias (,relu)
// ---------------------------------------------------------------------------
template <int F, int RELU>
__launch_bounds__(256)
__global__ void gatherh_kernel(const _Float16* __restrict__ h, const int* __restrict__ csr,
                               const int* __restrict__ offs, const float* __restrict__ dinv,
                               const float* __restrict__ bias, float* __restrict__ out, int N) {
    constexpr int L = F / 8;
    constexpr int NPB = 256 / L;
    const int n = blockIdx.x * NPB + threadIdx.x / L;
    const int c8 = (threadIdx.x % L) * 8;
    if (n >= N) return;

    const float di = dinv[n];
    half8v hs = *(const half8v*)&h[(long long)n * F + c8];
    float acc[8];
    const float sd = di * di;
#pragma unroll
    for (int j = 0; j < 8; ++j) acc[j] = (float)hs[j] * sd;

    const int end = offs[n + 1];
    for (int j = offs[n]; j < end; j += 8) {
        int s[8];
        float ws[8];
        half8v v[8];
#pragma unroll
        for (int u = 0; u < 8; ++u) {
            int jj = j + u;
            s[u] = csr[jj < end ? jj : end - 1];
        }
#pragma unroll
        for (int u = 0; u < 8; ++u)
            ws[u] = (j + u < end) ? dinv[s[u]] * di : 0.f;
#pragma unroll
        for (int u = 0; u < 8; ++u) v[u] = *(const half8v*)&h[(long long)s[u] * F + c8];
#pragma unroll
        for (int u = 0; u < 8; ++u) {
#pragma unroll
            for (int t = 0; t < 8; ++t) acc[t] = fmaf((float)v[u][t], ws[u], acc[t]);
        }
    }

    float4 b0 = *(const float4*)&bias[c8];
    float4 b1 = *(const float4*)&bias[c8 + 4];
    float bb[8] = {b0.x, b0.y, b0.z, b0.w, b1.x, b1.y, b1.z, b1.w};
#pragma unroll
    for (int t = 0; t < 8; ++t) {
        acc[t] += bb[t];
        if (RELU) acc[t] = fmaxf(acc[t], 0.f);
    }
    float* o = &out[(long long)n * F + c8];
    *(float4*)o       = make_float4(acc[0], acc[1], acc[2], acc[3]);
    *(float4*)(o + 4) = make_float4(acc[4], acc[5], acc[6], acc[7]);
}

extern "C" void kernel_launch(void* const* d_in, const int* in_sizes, int n_in,
                              void* d_out, int out_size, void* d_ws, size_t ws_size,
                              hipStream_t stream) {
    const float* x  = (const float*)d_in[0];
    const int*   ei = (const int*)d_in[1];
    const float* W1 = (const float*)d_in[2];
    const float* b1 = (const float*)d_in[3];
    const float* W2 = (const float*)d_in[4];
    const float* b2 = (const float*)d_in[5];
    float* out = (float*)d_out;

    const int IN_CH = 256, HID = 128, OUT = 64;
    const int N = in_sizes[0] / IN_CH;     // 50000
    const int E = in_sizes[1] / 2;         // 800000
    const int NB = (N + BUCK - 1) / BUCK;  // 782 buckets (< 1024)
    const int chunk = (E + NBLK - 1) / NBLK;

    char* w = (char*)d_ws;
    size_t off_b = 0;
    auto alloc = [&](size_t bytes) { void* p = w + off_b; off_b = (off_b + bytes + 255) & ~(size_t)255; return p; };
    int*   flag    = (int*)alloc(256);
    int*   hist2   = (int*)alloc((size_t)NBLK * NB * 4);
    int*   start2t = (int*)alloc((size_t)NB * NBLK * 4);
    int*   colsum  = (int*)alloc((size_t)NB * 4);
    int*   bbase   = (int*)alloc((size_t)(NB + 1) * 4);
    int*   offs    = (int*)alloc((size_t)(N + 1) * 4);
    float* dinv    = (float*)alloc((size_t)N * 4);
    unsigned* ebuf = (unsigned*)alloc((size_t)E * 4);
    int*   csr     = (int*)alloc((size_t)E * 4);
    _Float16* W1t  = (_Float16*)alloc((size_t)IN_CH * HID * 2);
    _Float16* W2t  = (_Float16*)alloc((size_t)HID * OUT * 2);
    _Float16* h1   = (_Float16*)alloc((size_t)N * HID * 2); // fp16; reused as h2
    float* agg1    = (float*)alloc((size_t)N * HID * 4);    // fp32
    _Float16* h2   = h1;

    const int T = 256;

    // --- preprocessing: cooperative single-kernel, fallback to chain -------
    PrepParams pp;
    pp.ei = ei; pp.E = E; pp.NB = NB; pp.chunk = chunk; pp.N = N;
    pp.hist2 = hist2; pp.start2t = start2t; pp.colsum = colsum; pp.bbase = bbase;
    pp.ebuf = ebuf; pp.offs = offs; pp.dinv = dinv; pp.csr = csr;
    pp.W1 = W1; pp.W1t = W1t; pp.W2 = W2; pp.W2t = W2t;
    void* args[] = { &pp };
    hipError_t cerr = hipLaunchCooperativeKernel((const void*)prep_kernel,
                                                 dim3(NBLK), dim3(256), args, 0, stream);
    if (cerr != hipSuccess) {
        detect64_kernel<<<1, 256, 0, stream>>>(ei, flag);
        hist2_kernel<<<NBLK, T, 0, stream>>>(ei, flag, hist2, E, NB, chunk);
        colscan_kernel<<<(NB + T - 1) / T, T, 0, stream>>>(hist2, start2t, colsum, NB);
        basescan_kernel<<<1, 1024, 0, stream>>>(colsum, bbase, NB, E);
        scatter2_kernel<<<NBLK, T, 0, stream>>>(ei, flag, bbase, start2t, ebuf, E, NB, chunk);
        csrbuild_kernel<<<NB, T, 0, stream>>>(ebuf, bbase, offs, dinv, csr, N, NB, E);
        int nb1 = (IN_CH * HID + T - 1) / T;
        int nb2 = (HID * OUT + T - 1) / T;
        convW_kernel<<<nb1 + nb2, T, 0, stream>>>(W1, W1t, IN_CH, HID, nb1,
                                                  W2, W2t, HID, OUT);
    }

    // GEMM1: h1[N,128](fp16) = x[N,256] @ W1
    gemm_f16_kernel<128, 256><<<(N + 127) / 128, 256, 0, stream>>>(x, W1t, h1, N);
    // layer-1 aggregation (fp16 gather, fused self-loop + bias + relu) -> agg1 (fp32)
    gatherh_kernel<128, 1><<<(N * 16 + 255) / 256, 256, 0, stream>>>(h1, csr, offs, dinv, b1, agg1, N);
    // GEMM2: h2[N,64](fp16) = agg1[N,128] @ W2
    gemm_f16_kernel<64, 128><<<(N + 127) / 128, 256, 0, stream>>>(agg1, W2t, h2, N);
    // layer-2 aggregation (fp16 gather, fused self-loop + bias) -> out (fp32)
    gatherh_kernel<64, 0><<<(N * 8 + 255) / 256, 256, 0, stream>>>(h2, csr, offs, dinv, b2, out, N);
}

// Round 12
// 275.783 us; speedup vs baseline: 1.5382x; 1.5382x over previous
//
#include <hip/hip_runtime.h>

// ---------------------------------------------------------------------------
// GCN encoder: out = GCNConv2( relu(GCNConv1(x)) )
// R11: R9 structure (best) with dispatch fusion, NO grid.sync (R10 showed
// cg::grid().sync() costs ~50us each at 1 block/CU):
//   hist2+convW+is64-detect -> scanall(colscan+basescan) -> scatter2 -> csrbuild
// GEMM = R7 async-LDS fp16 MFMA. Gathers = R9 clamped 8-edge rounds.
// ---------------------------------------------------------------------------

typedef __attribute__((ext_vector_type(4))) float floatx4;
typedef _Float16 __attribute__((ext_vector_type(8))) half8v;

#define BUCK_SH 6
#define BUCK    64           // dsts per bucket
#define NBLK    256          // blocks for hist2/scatter2

#define AS1(p) ((const __attribute__((address_space(1))) void*)(p))
#define AS3(p) ((__attribute__((address_space(3))) void*)(p))

__device__ __forceinline__ int edge_id(const int* __restrict__ ei, int is64, long long pos) {
    return is64 ? ei[2 * pos] : ei[(int)pos];
}

// per-block is64 detection: int64 node ids (<2^31) => odd dwords all zero.
// Same 256 words inspected by every block -> consistent verdict.
__device__ __forceinline__ int detect_is64(const int* __restrict__ ei) {
    __shared__ int nz;
    if (threadIdx.x == 0) nz = 0;
    __syncthreads();
    if (threadIdx.x < 256 && ei[2 * threadIdx.x + 1] != 0) atomicOr(&nz, 1);
    __syncthreads();
    return (nz == 0) ? 1 : 0;
}

// ---------------------------------------------------------------------------
// Weight pre-transform helper: W[K][Nc] fp32 -> Wt [Nc][K] fp16
// ---------------------------------------------------------------------------
__device__ __forceinline__ void convW_one(const float* W, _Float16* Wt, int K, int Nc, int idx) {
    if (idx >= K * Nc) return;
    int k = idx / Nc, n = idx % Nc;
    Wt[(long long)n * K + k] = (_Float16)W[idx];
}

// ---- fused: per-block bucket histogram + weight conversion -----------------
__global__ void __launch_bounds__(256)
hist2convW_kernel(const int* __restrict__ ei, int* __restrict__ hist2,
                  int E, int NB, int chunk,
                  const float* __restrict__ W1, _Float16* __restrict__ W1t,
                  const float* __restrict__ W2, _Float16* __restrict__ W2t) {
    __shared__ int h[1024];
    const int t = threadIdx.x;
    const int is64 = detect_is64(ei);
    for (int i = t; i < NB; i += 256) h[i] = 0;
    __syncthreads();
    const int lo = blockIdx.x * chunk;
    const int hi = min(E, lo + chunk);
    for (int e = lo + t; e < hi; e += 256) {
        int d = edge_id(ei, is64, (long long)E + e);
        atomicAdd(&h[d >> BUCK_SH], 1);
    }
    __syncthreads();
    for (int i = t; i < NB; i += 256) hist2[(long long)blockIdx.x * NB + i] = h[i];
    // weight conversion: 65536 grid threads cover 32768 + 8192 elements
    {
        int gtid = blockIdx.x * 256 + t;
        convW_one(W1, W1t, 256, 128, gtid);
        int g2 = gtid - 256 * 128;
        if (g2 >= 0) convW_one(W2, W2t, 128, 64, g2);
    }
}

// ---- fused colscan + basescan: one block, 1024 threads ---------------------
// thread t owns bucket t: walks hist2 column (coalesced), writes start2t row,
// then LDS exclusive scan of the 1024 column sums -> bbase.
__global__ void __launch_bounds__(1024)
scanall_kernel(const int* __restrict__ hist2, int* __restrict__ start2t,
               int* __restrict__ bbase, int NB, int E) {
    __shared__ int sm[1024];
    const int t = threadIdx.x;
    int col = 0;
    if (t < NB) {
        for (int b = 0; b < NBLK; ++b) {
            int v = hist2[(long long)b * NB + t];
            start2t[(long long)t * NBLK + b] = col;
            col += v;
        }
    }
    sm[t] = col;
    __syncthreads();
    for (int s = 1; s < 1024; s <<= 1) {
        int u = (t >= s) ? sm[t - s] : 0;
        __syncthreads();
        sm[t] += u;
        __syncthreads();
    }
    if (t < NB) bbase[t] = sm[t] - col;
    if (t == 0) bbase[NB] = E;
}

// ---- scatter: LDS cursors only, packed record src | (dlocal<<26) -----------
__global__ void __launch_bounds__(256)
scatter2_kernel(const int* __restrict__ ei, const int* __restrict__ bbase,
                const int* __restrict__ start2t, unsigned* __restrict__ ebuf,
                int E, int NB, int chunk) {
    __shared__ int hcur[1024];
    const int t = threadIdx.x;
    const int is64 = detect_is64(ei);
    for (int i = t; i < NB; i += 256)
        hcur[i] = bbase[i] + start2t[(long long)i * NBLK + blockIdx.x];
    __syncthreads();
    const int lo = blockIdx.x * chunk;
    const int hi = min(E, lo + chunk);
    for (int e = lo + t; e < hi; e += 256) {
        int s = edge_id(ei, is64, e);
        int d = edge_id(ei, is64, (long long)E + e);
        int pos = atomicAdd(&hcur[d >> BUCK_SH], 1);
        ebuf[pos] = (unsigned)s | ((unsigned)(d & (BUCK - 1)) << 26);
    }
}

// ---- per-bucket exact CSR build: offs, dinv, csr(src only) -----------------
__global__ void __launch_bounds__(256)
csrbuild_kernel(const unsigned* __restrict__ ebuf, const int* __restrict__ bbase,
                int* __restrict__ offs, float* __restrict__ dinv,
                int* __restrict__ csr, int N, int NB, int E) {
    __shared__ int cnt[BUCK], exc[BUCK], cur[BUCK];
    const int b = blockIdx.x;
    const int t = threadIdx.x;
    if (t < BUCK) { cnt[t] = 0; cur[t] = 0; }
    __syncthreads();
    const int lo = bbase[b], hi = bbase[b + 1];
    for (int i = lo + t; i < hi; i += blockDim.x)
        atomicAdd(&cnt[ebuf[i] >> 26], 1);
    __syncthreads();
    if (t == 0) {
        int run = 0;
        for (int l = 0; l < BUCK; ++l) { exc[l] = run; run += cnt[l]; }
    }
    __syncthreads();
    if (t < BUCK) {
        int n = b * BUCK + t;
        if (n < N) {
            offs[n] = lo + exc[t];
            dinv[n] = rsqrtf(1.0f + (float)cnt[t]);
        }
    }
    if (b == NB - 1 && t == 0) offs[N] = E;
    for (int i = lo + t; i < hi; i += blockDim.x) {
        unsigned e = ebuf[i];
        int l = e >> 26;
        int p = lo + exc[l] + atomicAdd(&cur[l], 1);
        csr[p] = (int)(e & 0x03FFFFFFu);
    }
}

// ---------------------------------------------------------------------------
// fp16 MFMA GEMM: C[M,NCOL](fp16) = A[M,K](fp32) @ B[K,NCOL]
// B pre-transposed fp16 [NCOL][K] (L2-resident). BM=128, BK=64, 4 waves,
// RT=2 row-tiles/wave. A staged fp32 via async global_load_lds (width 16),
// double-buffered, XOR-swizzled 16B units for conflict-free ds_read_b128.
// ---------------------------------------------------------------------------
template <int NCOL, int K>
__launch_bounds__(256)
__global__ void gemm_f16_kernel(const float* __restrict__ A,
                                const _Float16* __restrict__ Bt,
                                _Float16* __restrict__ C, int M) {
    constexpr int NCB = NCOL / 16;
    constexpr int BM = 128, BK = 64;
    constexpr int NC = K / BK;
    constexpr int UNITS = BM * BK / 4;
    __shared__ float As[2][BM * BK];

    const int tid  = threadIdx.x;
    const int wave = tid >> 6;
    const int lane = tid & 63;
    const int n15  = lane & 15;
    const int q    = lane >> 4;
    const int row0 = blockIdx.x * BM;

    floatx4 acc[2][NCB];
#pragma unroll
    for (int rt = 0; rt < 2; ++rt)
#pragma unroll
        for (int c = 0; c < NCB; ++c) acc[rt][c] = (floatx4){0.f, 0.f, 0.f, 0.f};

    auto stage = [&](int buf, int kc) {
#pragma unroll
        for (int j = 0; j < UNITS / 256; ++j) {
            int g = j * 256 + tid;
            int r = g >> 4;
            int u = (g & 15) ^ (r & 15);
            int gr = row0 + r;
            if (gr >= M) gr = M - 1;
            const float* gp = &A[(long long)gr * K + kc + u * 4];
            float* lp = &As[buf][g * 4];
            __builtin_amdgcn_global_load_lds(AS1(gp), AS3(lp), 16, 0, 0);
        }
    };

    stage(0, 0);
    __syncthreads();

#pragma unroll
    for (int c = 0; c < NC; ++c) {
        if (c + 1 < NC) stage((c + 1) & 1, (c + 1) * BK);
        const int buf = c & 1;
#pragma unroll
        for (int ks = 0; ks < 2; ++ks) {
            half8v af[2];
#pragma unroll
            for (int rt = 0; rt < 2; ++rt) {
                const int R = wave * 32 + rt * 16 + n15;
                const int u0 = ks * 8 + q * 2;
                const int p0 = (u0)     ^ (R & 15);
                const int p1 = (u0 + 1) ^ (R & 15);
                float4 f0 = *(const float4*)&As[buf][R * BK + p0 * 4];
                float4 f1 = *(const float4*)&As[buf][R * BK + p1 * 4];
                af[rt][0] = (_Float16)f0.x; af[rt][1] = (_Float16)f0.y;
                af[rt][2] = (_Float16)f0.z; af[rt][3] = (_Float16)f0.w;
                af[rt][4] = (_Float16)f1.x; af[rt][5] = (_Float16)f1.y;
                af[rt][6] = (_Float16)f1.z; af[rt][7] = (_Float16)f1.w;
            }
#pragma unroll
            for (int cb = 0; cb < NCB; ++cb) {
                const _Float16* bp = &Bt[(long long)(cb * 16 + n15) * K + c * BK + ks * 32 + q * 8];
                half8v bf = *(const half8v*)bp;
                acc[0][cb] = __builtin_amdgcn_mfma_f32_16x16x32_f16(af[0], bf, acc[0][cb], 0, 0, 0);
                acc[1][cb] = __builtin_amdgcn_mfma_f32_16x16x32_f16(af[1], bf, acc[1][cb], 0, 0, 0);
            }
        }
        if (c + 1 < NC) __syncthreads();
    }

#pragma unroll
    for (int rt = 0; rt < 2; ++rt) {
#pragma unroll
        for (int cb = 0; cb < NCB; ++cb) {
            int col = cb * 16 + n15;
#pragma unroll
            for (int r = 0; r < 4; ++r) {
                int gr = row0 + wave * 32 + rt * 16 + q * 4 + r;
                if (gr < M) C[(long long)gr * NCOL + col] = (_Float16)acc[rt][cb][r];
            }
        }
    }
}

// ---------------------------------------------------------------------------
// Gather aggregation, fp16 h, 8 channels/lane, clamped 8-edge rounds.
// out[n][:] = (h[n]*dinv[n]^2 + sum_e h[src]*dinv[src]*dinv[n]) + bias (,relu)
// ---------------------------------------------------------------------------
template <int F, int RELU>
__launch_bounds__(256)
__global__ void gatherh_kernel(const _Float16* __restrict__ h, const int* __restrict__ csr,
                               const int* __restrict__ offs, const float* __restrict__ dinv,
                               const float* __restrict__ bias, float* __restrict__ out, int N) {
    constexpr int L = F / 8;
    constexpr int NPB = 256 / L;
    const int n = blockIdx.x * NPB + threadIdx.x / L;
    const int c8 = (threadIdx.x % L) * 8;
    if (n >= N) return;

    const float di = dinv[n];
    half8v hs = *(const half8v*)&h[(long long)n * F + c8];
    float acc[8];
    const float sd = di * di;
#pragma unroll
    for (int j = 0; j < 8; ++j) acc[j] = (float)hs[j] * sd;

    const int end = offs[n + 1];
    for (int j = offs[n]; j < end; j += 8) {
        int s[8];
        float ws[8];
        half8v v[8];
#pragma unroll
        for (int u = 0; u < 8; ++u) {
            int jj = j + u;
            s[u] = csr[jj < end ? jj : end - 1];
        }
#pragma unroll
        for (int u = 0; u < 8; ++u)
            ws[u] = (j + u < end) ? dinv[s[u]] * di : 0.f;
#pragma unroll
        for (int u = 0; u < 8; ++u) v[u] = *(const half8v*)&h[(long long)s[u] * F + c8];
#pragma unroll
        for (int u = 0; u < 8; ++u) {
#pragma unroll
            for (int t = 0; t < 8; ++t) acc[t] = fmaf((float)v[u][t], ws[u], acc[t]);
        }
    }

    float4 b0 = *(const float4*)&bias[c8];
    float4 b1 = *(const float4*)&bias[c8 + 4];
    float bb[8] = {b0.x, b0.y, b0.z, b0.w, b1.x, b1.y, b1.z, b1.w};
#pragma unroll
    for (int t = 0; t < 8; ++t) {
        acc[t] += bb[t];
        if (RELU) acc[t] = fmaxf(acc[t], 0.f);
    }
    float* o = &out[(long long)n * F + c8];
    *(float4*)o       = make_float4(acc[0], acc[1], acc[2], acc[3]);
    *(float4*)(o + 4) = make_float4(acc[4], acc[5], acc[6], acc[7]);
}

extern "C" void kernel_launch(void* const* d_in, const int* in_sizes, int n_in,
                              void* d_out, int out_size, void* d_ws, size_t ws_size,
                              hipStream_t stream) {
    const float* x  = (const float*)d_in[0];
    const int*   ei = (const int*)d_in[1];
    const float* W1 = (const float*)d_in[2];
    const float* b1 = (const float*)d_in[3];
    const float* W2 = (const float*)d_in[4];
    const float* b2 = (const float*)d_in[5];
    float* out = (float*)d_out;

    const int IN_CH = 256, HID = 128, OUT = 64;
    const int N = in_sizes[0] / IN_CH;     // 50000
    const int E = in_sizes[1] / 2;         // 800000
    const int NB = (N + BUCK - 1) / BUCK;  // 782 buckets (< 1024)
    const int chunk = (E + NBLK - 1) / NBLK;

    char* w = (char*)d_ws;
    size_t off_b = 0;
    auto alloc = [&](size_t bytes) { void* p = w + off_b; off_b = (off_b + bytes + 255) & ~(size_t)255; return p; };
    int*   hist2   = (int*)alloc((size_t)NBLK * NB * 4);
    int*   start2t = (int*)alloc((size_t)NB * NBLK * 4);
    int*   bbase   = (int*)alloc((size_t)(NB + 1) * 4);
    int*   offs    = (int*)alloc((size_t)(N + 1) * 4);
    float* dinv    = (float*)alloc((size_t)N * 4);
    unsigned* ebuf = (unsigned*)alloc((size_t)E * 4);
    int*   csr     = (int*)alloc((size_t)E * 4);
    _Float16* W1t  = (_Float16*)alloc((size_t)IN_CH * HID * 2);
    _Float16* W2t  = (_Float16*)alloc((size_t)HID * OUT * 2);
    _Float16* h1   = (_Float16*)alloc((size_t)N * HID * 2); // fp16; reused as h2
    float* agg1    = (float*)alloc((size_t)N * HID * 4);    // fp32
    _Float16* h2   = h1;

    // --- preprocessing: 4 fused dispatches, no grid sync -------------------
    hist2convW_kernel<<<NBLK, 256, 0, stream>>>(ei, hist2, E, NB, chunk,
                                                W1, W1t, W2, W2t);
    scanall_kernel<<<1, 1024, 0, stream>>>(hist2, start2t, bbase, NB, E);
    scatter2_kernel<<<NBLK, 256, 0, stream>>>(ei, bbase, start2t, ebuf, E, NB, chunk);
    csrbuild_kernel<<<NB, 256, 0, stream>>>(ebuf, bbase, offs, dinv, csr, N, NB, E);

    // GEMM1: h1[N,128](fp16) = x[N,256] @ W1
    gemm_f16_kernel<128, 256><<<(N + 127) / 128, 256, 0, stream>>>(x, W1t, h1, N);
    // layer-1 aggregation (fp16 gather, fused self-loop + bias + relu) -> agg1 (fp32)
    gatherh_kernel<128, 1><<<(N * 16 + 255) / 256, 256, 0, stream>>>(h1, csr, offs, dinv, b1, agg1, N);
    // GEMM2: h2[N,64](fp16) = agg1[N,128] @ W2
    gemm_f16_kernel<64, 128><<<(N + 127) / 128, 256, 0, stream>>>(agg1, W2t, h2, N);
    // layer-2 aggregation (fp16 gather, fused self-loop + bias) -> out (fp32)
    gatherh_kernel<64, 0><<<(N * 8 + 255) / 256, 256, 0, stream>>>(h2, csr, offs, dinv, b2, out, N);
}

// Round 13
// 215.325 us; speedup vs baseline: 1.9701x; 1.2808x over previous
//
#include <hip/hip_runtime.h>

// ---------------------------------------------------------------------------
// GCN encoder: out = GCNConv2( relu(GCNConv1(x)) )
// R12: R11 minus the single-block scanall regression. Column scans now run
// one WAVE per bucket (wavescan, shuffle-scan, fully parallel) + tiny
// basescan. hist2+convW+is64 fusion kept. GEMM = R7 async-LDS fp16 MFMA.
// Gathers = R9 clamped 8-edge rounds.
// ---------------------------------------------------------------------------

typedef __attribute__((ext_vector_type(4))) float floatx4;
typedef _Float16 __attribute__((ext_vector_type(8))) half8v;

#define BUCK_SH 6
#define BUCK    64           // dsts per bucket
#define NBLK    256          // blocks for hist2/scatter2

#define AS1(p) ((const __attribute__((address_space(1))) void*)(p))
#define AS3(p) ((__attribute__((address_space(3))) void*)(p))

__device__ __forceinline__ int edge_id(const int* __restrict__ ei, int is64, long long pos) {
    return is64 ? ei[2 * pos] : ei[(int)pos];
}

// per-block is64 detection: int64 node ids (<2^31) => odd dwords all zero.
// Same 256 words inspected by every block -> consistent verdict.
__device__ __forceinline__ int detect_is64(const int* __restrict__ ei) {
    __shared__ int nz;
    if (threadIdx.x == 0) nz = 0;
    __syncthreads();
    if (threadIdx.x < 256 && ei[2 * threadIdx.x + 1] != 0) atomicOr(&nz, 1);
    __syncthreads();
    return (nz == 0) ? 1 : 0;
}

// ---------------------------------------------------------------------------
// Weight pre-transform helper: W[K][Nc] fp32 -> Wt [Nc][K] fp16
// ---------------------------------------------------------------------------
__device__ __forceinline__ void convW_one(const float* W, _Float16* Wt, int K, int Nc, int idx) {
    if (idx >= K * Nc) return;
    int k = idx / Nc, n = idx % Nc;
    Wt[(long long)n * K + k] = (_Float16)W[idx];
}

// ---- fused: per-block bucket histogram + weight conversion -----------------
__global__ void __launch_bounds__(256)
hist2convW_kernel(const int* __restrict__ ei, int* __restrict__ hist2,
                  int E, int NB, int chunk,
                  const float* __restrict__ W1, _Float16* __restrict__ W1t,
                  const float* __restrict__ W2, _Float16* __restrict__ W2t) {
    __shared__ int h[1024];
    const int t = threadIdx.x;
    const int is64 = detect_is64(ei);
    for (int i = t; i < NB; i += 256) h[i] = 0;
    __syncthreads();
    const int lo = blockIdx.x * chunk;
    const int hi = min(E, lo + chunk);
    for (int e = lo + t; e < hi; e += 256) {
        int d = edge_id(ei, is64, (long long)E + e);
        atomicAdd(&h[d >> BUCK_SH], 1);
    }
    __syncthreads();
    for (int i = t; i < NB; i += 256) hist2[(long long)blockIdx.x * NB + i] = h[i];
    // weight conversion: 65536 grid threads cover 32768 + 8192 elements
    {
        int gtid = blockIdx.x * 256 + t;
        convW_one(W1, W1t, 256, 128, gtid);
        int g2 = gtid - 256 * 128;
        if (g2 >= 0) convW_one(W2, W2t, 128, 64, g2);
    }
}

// ---- wavescan: ONE WAVE PER BUCKET, shuffle-scan over the 256 block counts -
// start2t[bucket][blk] = exclusive prefix; colsum[bucket] = total.
__global__ void __launch_bounds__(256)
wavescan_kernel(const int* __restrict__ hist2, int* __restrict__ start2t,
                int* __restrict__ colsum, int NB) {
    const int wid  = (blockIdx.x * 256 + threadIdx.x) >> 6;   // bucket id
    const int lane = threadIdx.x & 63;
    if (wid >= NB) return;
    int carry = 0;
    for (int c = 0; c < NBLK; c += 64) {
        int v = hist2[(long long)(c + lane) * NB + wid];
        int incl = v;
#pragma unroll
        for (int s = 1; s < 64; s <<= 1) {
            int u = __shfl_up(incl, s, 64);
            if (lane >= s) incl += u;
        }
        start2t[(long long)wid * NBLK + c + lane] = carry + incl - v;   // exclusive
        carry += __shfl(incl, 63, 64);
    }
    if (lane == 0) colsum[wid] = carry;
}

// ---- tiny single-block exclusive scan of colsum -> bbase[NB+1] -------------
__global__ void __launch_bounds__(1024)
basescan_kernel(const int* __restrict__ colsum, int* __restrict__ bbase, int NB, int E) {
    __shared__ int sm[1024];
    const int t = threadIdx.x;
    int v = (t < NB) ? colsum[t] : 0;
    sm[t] = v;
    __syncthreads();
    for (int s = 1; s < 1024; s <<= 1) {
        int u = (t >= s) ? sm[t - s] : 0;
        __syncthreads();
        sm[t] += u;
        __syncthreads();
    }
    if (t < NB) bbase[t] = sm[t] - v;
    if (t == 0) bbase[NB] = E;
}

// ---- scatter: LDS cursors only, packed record src | (dlocal<<26) -----------
__global__ void __launch_bounds__(256)
scatter2_kernel(const int* __restrict__ ei, const int* __restrict__ bbase,
                const int* __restrict__ start2t, unsigned* __restrict__ ebuf,
                int E, int NB, int chunk) {
    __shared__ int hcur[1024];
    const int t = threadIdx.x;
    const int is64 = detect_is64(ei);
    for (int i = t; i < NB; i += 256)
        hcur[i] = bbase[i] + start2t[(long long)i * NBLK + blockIdx.x];
    __syncthreads();
    const int lo = blockIdx.x * chunk;
    const int hi = min(E, lo + chunk);
    for (int e = lo + t; e < hi; e += 256) {
        int s = edge_id(ei, is64, e);
        int d = edge_id(ei, is64, (long long)E + e);
        int pos = atomicAdd(&hcur[d >> BUCK_SH], 1);
        ebuf[pos] = (unsigned)s | ((unsigned)(d & (BUCK - 1)) << 26);
    }
}

// ---- per-bucket exact CSR build: offs, dinv, csr(src only) -----------------
__global__ void __launch_bounds__(256)
csrbuild_kernel(const unsigned* __restrict__ ebuf, const int* __restrict__ bbase,
                int* __restrict__ offs, float* __restrict__ dinv,
                int* __restrict__ csr, int N, int NB, int E) {
    __shared__ int cnt[BUCK], exc[BUCK], cur[BUCK];
    const int b = blockIdx.x;
    const int t = threadIdx.x;
    if (t < BUCK) { cnt[t] = 0; cur[t] = 0; }
    __syncthreads();
    const int lo = bbase[b], hi = bbase[b + 1];
    for (int i = lo + t; i < hi; i += blockDim.x)
        atomicAdd(&cnt[ebuf[i] >> 26], 1);
    __syncthreads();
    if (t == 0) {
        int run = 0;
        for (int l = 0; l < BUCK; ++l) { exc[l] = run; run += cnt[l]; }
    }
    __syncthreads();
    if (t < BUCK) {
        int n = b * BUCK + t;
        if (n < N) {
            offs[n] = lo + exc[t];
            dinv[n] = rsqrtf(1.0f + (float)cnt[t]);
        }
    }
    if (b == NB - 1 && t == 0) offs[N] = E;
    for (int i = lo + t; i < hi; i += blockDim.x) {
        unsigned e = ebuf[i];
        int l = e >> 26;
        int p = lo + exc[l] + atomicAdd(&cur[l], 1);
        csr[p] = (int)(e & 0x03FFFFFFu);
    }
}

// ---------------------------------------------------------------------------
// fp16 MFMA GEMM: C[M,NCOL](fp16) = A[M,K](fp32) @ B[K,NCOL]
// B pre-transposed fp16 [NCOL][K] (L2-resident). BM=128, BK=64, 4 waves,
// RT=2 row-tiles/wave. A staged fp32 via async global_load_lds (width 16),
// double-buffered, XOR-swizzled 16B units for conflict-free ds_read_b128.
// ---------------------------------------------------------------------------
template <int NCOL, int K>
__launch_bounds__(256)
__global__ void gemm_f16_kernel(const float* __restrict__ A,
                                const _Float16* __restrict__ Bt,
                                _Float16* __restrict__ C, int M) {
    constexpr int NCB = NCOL / 16;
    constexpr int BM = 128, BK = 64;
    constexpr int NC = K / BK;
    constexpr int UNITS = BM * BK / 4;
    __shared__ float As[2][BM * BK];

    const int tid  = threadIdx.x;
    const int wave = tid >> 6;
    const int lane = tid & 63;
    const int n15  = lane & 15;
    const int q    = lane >> 4;
    const int row0 = blockIdx.x * BM;

    floatx4 acc[2][NCB];
#pragma unroll
    for (int rt = 0; rt < 2; ++rt)
#pragma unroll
        for (int c = 0; c < NCB; ++c) acc[rt][c] = (floatx4){0.f, 0.f, 0.f, 0.f};

    auto stage = [&](int buf, int kc) {
#pragma unroll
        for (int j = 0; j < UNITS / 256; ++j) {
            int g = j * 256 + tid;
            int r = g >> 4;
            int u = (g & 15) ^ (r & 15);
            int gr = row0 + r;
            if (gr >= M) gr = M - 1;
            const float* gp = &A[(long long)gr * K + kc + u * 4];
            float* lp = &As[buf][g * 4];
            __builtin_amdgcn_global_load_lds(AS1(gp), AS3(lp), 16, 0, 0);
        }
    };

    stage(0, 0);
    __syncthreads();

#pragma unroll
    for (int c = 0; c < NC; ++c) {
        if (c + 1 < NC) stage((c + 1) & 1, (c + 1) * BK);
        const int buf = c & 1;
#pragma unroll
        for (int ks = 0; ks < 2; ++ks) {
            half8v af[2];
#pragma unroll
            for (int rt = 0; rt < 2; ++rt) {
                const int R = wave * 32 + rt * 16 + n15;
                const int u0 = ks * 8 + q * 2;
                const int p0 = (u0)     ^ (R & 15);
                const int p1 = (u0 + 1) ^ (R & 15);
                float4 f0 = *(const float4*)&As[buf][R * BK + p0 * 4];
                float4 f1 = *(const float4*)&As[buf][R * BK + p1 * 4];
                af[rt][0] = (_Float16)f0.x; af[rt][1] = (_Float16)f0.y;
                af[rt][2] = (_Float16)f0.z; af[rt][3] = (_Float16)f0.w;
                af[rt][4] = (_Float16)f1.x; af[rt][5] = (_Float16)f1.y;
                af[rt][6] = (_Float16)f1.z; af[rt][7] = (_Float16)f1.w;
            }
#pragma unroll
            for (int cb = 0; cb < NCB; ++cb) {
                const _Float16* bp = &Bt[(long long)(cb * 16 + n15) * K + c * BK + ks * 32 + q * 8];
                half8v bf = *(const half8v*)bp;
                acc[0][cb] = __builtin_amdgcn_mfma_f32_16x16x32_f16(af[0], bf, acc[0][cb], 0, 0, 0);
                acc[1][cb] = __builtin_amdgcn_mfma_f32_16x16x32_f16(af[1], bf, acc[1][cb], 0, 0, 0);
            }
        }
        if (c + 1 < NC) __syncthreads();
    }

#pragma unroll
    for (int rt = 0; rt < 2; ++rt) {
#pragma unroll
        for (int cb = 0; cb < NCB; ++cb) {
            int col = cb * 16 + n15;
#pragma unroll
            for (int r = 0; r < 4; ++r) {
                int gr = row0 + wave * 32 + rt * 16 + q * 4 + r;
                if (gr < M) C[(long long)gr * NCOL + col] = (_Float16)acc[rt][cb][r];
            }
        }
    }
}

// ---------------------------------------------------------------------------
// Gather aggregation, fp16 h, 8 channels/lane, clamped 8-edge rounds.
// out[n][:] = (h[n]*dinv[n]^2 + sum_e h[src]*dinv[src]*dinv[n]) + bias (,relu)
// ---------------------------------------------------------------------------
template <int F, int RELU>
__launch_bounds__(256)
__global__ void gatherh_kernel(const _Float16* __restrict__ h, const int* __restrict__ csr,
                               const int* __restrict__ offs, const float* __restrict__ dinv,
                               const float* __restrict__ bias, float* __restrict__ out, int N) {
    constexpr int L = F / 8;
    constexpr int NPB = 256 / L;
    const int n = blockIdx.x * NPB + threadIdx.x / L;
    const int c8 = (threadIdx.x % L) * 8;
    if (n >= N) return;

    const float di = dinv[n];
    half8v hs = *(const half8v*)&h[(long long)n * F + c8];
    float acc[8];
    const float sd = di * di;
#pragma unroll
    for (int j = 0; j < 8; ++j) acc[j] = (float)hs[j] * sd;

    const int end = offs[n + 1];
    for (int j = offs[n]; j < end; j += 8) {
        int s[8];
        float ws[8];
        half8v v[8];
#pragma unroll
        for (int u = 0; u < 8; ++u) {
            int jj = j + u;
            s[u] = csr[jj < end ? jj : end - 1];
        }
#pragma unroll
        for (int u = 0; u < 8; ++u)
            ws[u] = (j + u < end) ? dinv[s[u]] * di : 0.f;
#pragma unroll
        for (int u = 0; u < 8; ++u) v[u] = *(const half8v*)&h[(long long)s[u] * F + c8];
#pragma unroll
        for (int u = 0; u < 8; ++u) {
#pragma unroll
            for (int t = 0; t < 8; ++t) acc[t] = fmaf((float)v[u][t], ws[u], acc[t]);
        }
    }

    float4 b0 = *(const float4*)&bias[c8];
    float4 b1 = *(const float4*)&bias[c8 + 4];
    float bb[8] = {b0.x, b0.y, b0.z, b0.w, b1.x, b1.y, b1.z, b1.w};
#pragma unroll
    for (int t = 0; t < 8; ++t) {
        acc[t] += bb[t];
        if (RELU) acc[t] = fmaxf(acc[t], 0.f);
    }
    float* o = &out[(long long)n * F + c8];
    *(float4*)o       = make_float4(acc[0], acc[1], acc[2], acc[3]);
    *(float4*)(o + 4) = make_float4(acc[4], acc[5], acc[6], acc[7]);
}

extern "C" void kernel_launch(void* const* d_in, const int* in_sizes, int n_in,
                              void* d_out, int out_size, void* d_ws, size_t ws_size,
                              hipStream_t stream) {
    const float* x  = (const float*)d_in[0];
    const int*   ei = (const int*)d_in[1];
    const float* W1 = (const float*)d_in[2];
    const float* b1 = (const float*)d_in[3];
    const float* W2 = (const float*)d_in[4];
    const float* b2 = (const float*)d_in[5];
    float* out = (float*)d_out;

    const int IN_CH = 256, HID = 128, OUT = 64;
    const int N = in_sizes[0] / IN_CH;     // 50000
    const int E = in_sizes[1] / 2;         // 800000
    const int NB = (N + BUCK - 1) / BUCK;  // 782 buckets (< 1024)
    const int chunk = (E + NBLK - 1) / NBLK;

    char* w = (char*)d_ws;
    size_t off_b = 0;
    auto alloc = [&](size_t bytes) { void* p = w + off_b; off_b = (off_b + bytes + 255) & ~(size_t)255; return p; };
    int*   hist2   = (int*)alloc((size_t)NBLK * NB * 4);
    int*   start2t = (int*)alloc((size_t)NB * NBLK * 4);
    int*   colsum  = (int*)alloc((size_t)NB * 4);
    int*   bbase   = (int*)alloc((size_t)(NB + 1) * 4);
    int*   offs    = (int*)alloc((size_t)(N + 1) * 4);
    float* dinv    = (float*)alloc((size_t)N * 4);
    unsigned* ebuf = (unsigned*)alloc((size_t)E * 4);
    int*   csr     = (int*)alloc((size_t)E * 4);
    _Float16* W1t  = (_Float16*)alloc((size_t)IN_CH * HID * 2);
    _Float16* W2t  = (_Float16*)alloc((size_t)HID * OUT * 2);
    _Float16* h1   = (_Float16*)alloc((size_t)N * HID * 2); // fp16; reused as h2
    float* agg1    = (float*)alloc((size_t)N * HID * 4);    // fp32
    _Float16* h2   = h1;

    // --- preprocessing: 5 dispatches, fully parallel scans -----------------
    hist2convW_kernel<<<NBLK, 256, 0, stream>>>(ei, hist2, E, NB, chunk,
                                                W1, W1t, W2, W2t);
    wavescan_kernel<<<(NB * 64 + 255) / 256, 256, 0, stream>>>(hist2, start2t, colsum, NB);
    basescan_kernel<<<1, 1024, 0, stream>>>(colsum, bbase, NB, E);
    scatter2_kernel<<<NBLK, 256, 0, stream>>>(ei, bbase, start2t, ebuf, E, NB, chunk);
    csrbuild_kernel<<<NB, 256, 0, stream>>>(ebuf, bbase, offs, dinv, csr, N, NB, E);

    // GEMM1: h1[N,128](fp16) = x[N,256] @ W1
    gemm_f16_kernel<128, 256><<<(N + 127) / 128, 256, 0, stream>>>(x, W1t, h1, N);
    // layer-1 aggregation (fp16 gather, fused self-loop + bias + relu) -> agg1 (fp32)
    gatherh_kernel<128, 1><<<(N * 16 + 255) / 256, 256, 0, stream>>>(h1, csr, offs, dinv, b1, agg1, N);
    // GEMM2: h2[N,64](fp16) = agg1[N,128] @ W2
    gemm_f16_kernel<64, 128><<<(N + 127) / 128, 256, 0, stream>>>(agg1, W2t, h2, N);
    // layer-2 aggregation (fp16 gather, fused self-loop + bias) -> out (fp32)
    gatherh_kernel<64, 0><<<(N * 8 + 255) / 256, 256, 0, stream>>>(h2, csr, offs, dinv, b2, out, N);
}